// Round 3
// 879.468 us; speedup vs baseline: 1.0333x; 1.0333x over previous
//
#include <hip/hip_runtime.h>
#include <stdint.h>

// Depthwise conv2d 31x31, pad 15, stride 1. fp32 in/out, fp16 dot2 inner.
// v5: kh-paired dot2 on a plain transposed LDS tile (column stride 176 B,
// 16B-aligned -> ds_read_b128; stride/16 = 11 is coprime to 8 bank-quads
// so b128 reads are conflict-free without any swizzle). Weight pair tables
// (wa = odd rows, wb = even rows) packed per-block into LDS as half2v and
// register-cached per kw. No bit_cast, no swizzle, no d_ws. 128 thr = 2
// waves x 28 rows.

#define DIMC 384
#define HW 56
#define KS 31
#define RH 28            // output rows per thread
#define NM 16            // kh pairs (31 -> 16, padded with 0)
#define TW 86            // tile columns: global cols -15..70
#define TH 88            // h slots per column (hs = h+16, 0..87); 176 B stride

typedef _Float16 half2v __attribute__((ext_vector_type(2)));
typedef _Float16 half8v __attribute__((ext_vector_type(8)));

__device__ __forceinline__ float dot2f(half2v a, half2v b, float c) {
#if defined(__has_builtin) && __has_builtin(__builtin_amdgcn_fdot2)
    return __builtin_amdgcn_fdot2(a, b, c, false);
#else
    return fmaf((float)a.x, (float)b.x, fmaf((float)a.y, (float)b.y, c));
#endif
}

// out[r] = sum_i x[i] * w[i - r + 15], i in [r-15, r+15].
// Tile pair p holds (x[2p-16], x[2p-15]) (hs = 2p, 2p+1).
//   r even: first pair p0 = r/2,     pair m uses wb = (w[2m-1], w[2m]), w[-1]=0
//   r odd : first pair p0 = (r+1)/2, pair m uses wa = (w[2m],   w[2m+1]), w[31]=0
// Rows r = 28G + j; parity(r) = parity(j); p0 = 14G + ceil(j/2).
template<int G>
__device__ __forceinline__ void conv_cols(const _Float16* __restrict__ tile,
                                          const half2v* __restrict__ wlds,
                                          int tx, float* __restrict__ acc)
{
    constexpr int P0 = 14 * G;        // pairs needed: P0 .. P0+29
    constexpr int AG = P0 & ~3;       // 16B-aligned start pair: 0 / 12
    constexpr int DG = P0 - AG;       // X index offset: 0 / 2
    // X holds pairs AG..AG+31; G=1 reaches pair 43 -> hs 87 (in range).

#pragma unroll 1
    for (int kw = 0; kw < KS; ++kw) {
        const int col = tx + kw;                      // tile column (<= 85)
        const char* cbase = (const char*)tile + col * (TH * 2) + AG * 4;

        half2v X[32];                                  // pairs AG..AG+31
#pragma unroll
        for (int q = 0; q < 8; ++q) {
            half8v r = *(const half8v*)(cbase + 16 * q);   // ds_read_b128
            X[4 * q + 0] = __builtin_shufflevector(r, r, 0, 1);
            X[4 * q + 1] = __builtin_shufflevector(r, r, 2, 3);
            X[4 * q + 2] = __builtin_shufflevector(r, r, 4, 5);
            X[4 * q + 3] = __builtin_shufflevector(r, r, 6, 7);
        }

        half2v Wt[32];                                 // [0..15]=wa, [16..31]=wb
        const char* wbase = (const char*)wlds + (kw << 7);  // uniform -> bcast
#pragma unroll
        for (int q = 0; q < 8; ++q) {
            half8v r = *(const half8v*)(wbase + 16 * q);
            Wt[4 * q + 0] = __builtin_shufflevector(r, r, 0, 1);
            Wt[4 * q + 1] = __builtin_shufflevector(r, r, 2, 3);
            Wt[4 * q + 2] = __builtin_shufflevector(r, r, 4, 5);
            Wt[4 * q + 3] = __builtin_shufflevector(r, r, 6, 7);
        }

#pragma unroll
        for (int j = 0; j < RH; ++j) {
            const int off = DG + ((j + (j & 1)) >> 1);   // compile-time
            const int ws  = (j & 1) ? 0 : 16;            // odd: wa, even: wb
#pragma unroll
            for (int m = 0; m < NM; ++m)
                acc[j] = dot2f(X[off + m], Wt[ws + m], acc[j]);
        }
    }
}

__global__ __launch_bounds__(128, 4)
void dwconv31_v5(const float* __restrict__ x, const float* __restrict__ w,
                 const float* __restrict__ bias, float* __restrict__ out)
{
    __shared__ __align__(16) _Float16 tile[TW * TH];     // 15,136 B
    __shared__ __align__(16) half2v  wlds[KS * 32];      //  3,968 B

    const int plane = blockIdx.x;              // n*384 + c
    const int c = plane % DIMC;
    const float* __restrict__ xp = x + (size_t)plane * (HW * HW);
    const float* __restrict__ wc = w + (size_t)c * (KS * KS);
    const int tid = threadIdx.x;

    // ---- pack fp16 weight-pair tables into LDS ----
    for (int i = tid; i < KS * NM; i += 128) {
        int kw = i >> 4, m = i & (NM - 1);
        float t0 = wc[(2 * m) * KS + kw];                              // w[2m]
        float t1 = (2 * m + 1 < KS) ? wc[(2 * m + 1) * KS + kw] : 0.0f;
        float tm = (m > 0)          ? wc[(2 * m - 1) * KS + kw] : 0.0f;
        half2v wa; wa.x = (_Float16)t0; wa.y = (_Float16)t1;           // odd r
        half2v wb; wb.x = (_Float16)tm; wb.y = (_Float16)t0;           // even r
        wlds[(kw << 5) + m]      = wa;
        wlds[(kw << 5) + NM + m] = wb;
    }

    // ---- stage transposed tile: tile[col*TH + hs] = x[hs-16][col-15] ----
    // col fastest across lanes -> coalesced global reads; b16 LDS writes.
    for (int idx = tid; idx < TW * TH; idx += 128) {
        int hs   = idx / TW;
        int wcol = idx - hs * TW;
        int h = hs - 16, gc = wcol - 15;
        float v = 0.0f;
        if ((unsigned)h < (unsigned)HW && (unsigned)gc < (unsigned)HW)
            v = xp[h * HW + gc];
        tile[wcol * TH + hs] = (_Float16)v;
    }
    __syncthreads();

    const int tx = tid & 63;              // output column (active if < 56)
    const int g  = tid >> 6;              // row group: rows g*28 .. g*28+27

    if (tx < HW) {
        float acc[RH];
#pragma unroll
        for (int j = 0; j < RH; ++j) acc[j] = 0.0f;

        if (g == 0) conv_cols<0>(tile, wlds, tx, acc);
        else        conv_cols<1>(tile, wlds, tx, acc);

        const float b = bias[c];
        const int h0 = g * RH;
        float* __restrict__ op = out + (size_t)plane * (HW * HW);
#pragma unroll
        for (int j = 0; j < RH; ++j)
            op[(h0 + j) * HW + tx] = acc[j] + b;
    }
}

extern "C" void kernel_launch(void* const* d_in, const int* in_sizes, int n_in,
                              void* d_out, int out_size, void* d_ws, size_t ws_size,
                              hipStream_t stream) {
    const float* x    = (const float*)d_in[0];
    const float* wgt  = (const float*)d_in[1];
    const float* bias = (const float*)d_in[2];
    float* out = (float*)d_out;

    const int nplanes = 32 * DIMC;         // one block per (n,c) plane
    dwconv31_v5<<<nplanes, 128, 0, stream>>>(x, wgt, bias, out);
}